// Round 11
// baseline (113.171 us; speedup 1.0000x reference)
//
#include <hip/hip_runtime.h>
#include <math.h>

// P2V: out[b,dhw] = top2-margin over n of softmax_n( |s2| * exp(-|s1| * dist) )
// dist = |x|^2 + |g|^2 - 2 x.g
//
// Round 11: model fitting ALL rounds: dur = max(LDS-port, VALU). R2/R8/R10
// issue 8192 ds_read_b128/CU = 98K cyc = 41us -> the invariant LDS-port floor
// (one 16B LDS read per (output,n) operand per lane). Break it: hold the
// per-n table in REGISTERS (16 float4/lane = the wave's 64 lanes cover all
// 1024 n), wave processes 16 outputs sequentially:
//   per output: readlane-broadcast g (3), each lane does its 16 n
//   (9 main + 1 trans, R10 poly math), then 6-step DPP reduction (rocPRIM
//   row_shr 1/2/4/8 + row_bcast15/31 -> lane 63) of (top0, top1, S) on the
//   MAIN pipe - zero LDS in the hot loop.
//
// Math (= R10): q = -c1|x|^2 + 2c1(x.g); u = 2^q; v = Ct*u;
//   fast (s2a<=1): e^v ~ PC0 + u*Q(u), Q Horner with Ct^k folded; d0 cancels
//   in num, S_true = 1024*PC0 + S_red.  general: shifted 2-exp path.

#define LOG2E 1.44269504088896340736f
// deg-4 minimax (Chebyshev) coeffs for e^x on [0,1], abs err <= 2.8e-5
#define PC0 1.0000247f
#define PC1 0.9987113f
#define PC2 0.5099871f
#define PC3 0.1399751f
#define PC4 0.0695533f

template<int CTRL, int RM, int BM>
__device__ __forceinline__ float dpp_f(float x, float id) {
    return __int_as_float(__builtin_amdgcn_update_dpp(
        __float_as_int(id), __float_as_int(x), CTRL, RM, BM, false));
}

__device__ __forceinline__ float rlane_f(float x, int l) {
    return __int_as_float(__builtin_amdgcn_readlane(__float_as_int(x), l));
}

// one tree step of the 64-lane (top0, top1, sum) reduction
template<int CTRL, int RM, int BM>
__device__ __forceinline__ void red_step(float& t0, float& t1, float& S) {
    const float a0 = dpp_f<CTRL, RM, BM>(t0, -INFINITY);
    const float a1 = dpp_f<CTRL, RM, BM>(t1, -INFINITY);
    const float aS = dpp_f<CTRL, RM, BM>(S, 0.f);
    t1 = fmaxf(fmaxf(t1, a1), fminf(t0, a0));   // merge two top-2 sets
    t0 = fmaxf(t0, a0);
    S += aS;
}

__device__ __forceinline__ void red64(float& t0, float& t1, float& S) {
    red_step<0x111, 0xF, 0xF>(t0, t1, S);   // row_shr:1
    red_step<0x112, 0xF, 0xF>(t0, t1, S);   // row_shr:2
    red_step<0x114, 0xF, 0xE>(t0, t1, S);   // row_shr:4, bank_mask 0xE
    red_step<0x118, 0xF, 0xC>(t0, t1, S);   // row_shr:8, bank_mask 0xC
    red_step<0x142, 0xA, 0xF>(t0, t1, S);   // row_bcast15, rows 1,3
    red_step<0x143, 0x8, 0xF>(t0, t1, S);   // row_bcast31, row 3 -> lane 63
}

__global__ __launch_bounds__(256, 4) void p2v_kernel(
    const float* __restrict__ xyz,   // (B=4, C=3, N=1024)
    const float* __restrict__ grid,  // (C=3, 32768)
    const float* __restrict__ s1,
    const float* __restrict__ s2,
    float* __restrict__ out)         // (B=4, 32768)
{
    __shared__ float4 A[1024];

    const int tid  = threadIdx.x;
    const int lane = tid & 63;
    const int wv   = tid >> 6;                     // wave 0..3
    const int b    = blockIdx.x >> 9;              // 512 blocks per b
    const int k    = blockIdx.x & 511;             // 64 outputs per block
    const int obase = (k << 6) + (wv << 4);        // this wave's 16 outputs

    const float s1a = fabsf(s1[0]);
    const float s2a = fabsf(s2[0]);
    const float c1  = LOG2E * s1a;

    // stage per-n table once per block
    const float* xb = xyz + b * 3072;
    #pragma unroll
    for (int i = 0; i < 4; ++i) {
        const int n = tid + i * 256;
        const float x = xb[n], y = xb[1024 + n], z = xb[2048 + n];
        const float x2 = fmaf(x, x, fmaf(y, y, z * z));
        A[n] = make_float4(-c1 * x2, 2.f * c1 * x, 2.f * c1 * y, 2.f * c1 * z);
    }
    __syncthreads();

    // lane's register-resident slice: n = lane + 64j (16 LDS reads TOTAL)
    float4 tab[16];
    #pragma unroll
    for (int j = 0; j < 16; ++j) tab[j] = A[lane + (j << 6)];

    // lane i<16 holds g for output obase+i (readlane-broadcast later)
    const int gi = obase + (lane & 15);
    const float gv0 = grid[gi];
    const float gv1 = grid[32768 + gi];
    const float gv2 = grid[65536 + gi];

    const bool fast = (s2a <= 1.0f);               // wave-uniform branch
    float res = 0.f;

    for (int o = 0; o < 16; ++o) {
        const float g0 = rlane_f(gv0, o);
        const float g1 = rlane_f(gv1, o);
        const float g2 = rlane_f(gv2, o);
        const float Ct = s2a * __builtin_amdgcn_exp2f(
            -c1 * fmaf(g0, g0, fmaf(g1, g1, g2 * g2)));

        float t0E = -INFINITY, t1E = -INFINITY, t0O = -INFINITY, t1O = -INFINITY;
        float S0 = 0.f, S1 = 0.f;
        float val;

        if (fast) {
            const float Ct2 = Ct * Ct;
            const float d1 = PC1 * Ct;
            const float d2 = PC2 * Ct2;
            const float d3 = PC3 * Ct2 * Ct;
            const float d4 = PC4 * Ct2 * Ct2;
            #pragma unroll
            for (int j = 0; j < 16; ++j) {
                const float4 a = tab[j];
                const float q = fmaf(g0, a.y, fmaf(g1, a.z, fmaf(g2, a.w, a.x)));
                if (j & 1) {
                    t1O = __builtin_amdgcn_fmed3f(t0O, t1O, q); t0O = fmaxf(t0O, q);
                } else {
                    t1E = __builtin_amdgcn_fmed3f(t0E, t1E, q); t0E = fmaxf(t0E, q);
                }
                const float u = __builtin_amdgcn_exp2f(q);
                float Q = fmaf(d4, u, d3);
                Q = fmaf(Q, u, d2);
                Q = fmaf(Q, u, d1);
                if (j & 1) S1 = fmaf(Q, u, S1); else S0 = fmaf(Q, u, S0);
            }
            float t0 = fmaxf(t0E, t0O);
            float t1 = fmaxf(fminf(t0E, t0O), fmaxf(t1E, t1O));
            float S  = S0 + S1;
            red64(t0, t1, S);
            const float t0s = rlane_f(t0, 63);
            const float t1s = rlane_f(t1, 63);
            const float Ss  = rlane_f(S, 63);
            const float u0 = __builtin_amdgcn_exp2f(t0s);
            const float u1 = __builtin_amdgcn_exp2f(t1s);
            float Q0 = fmaf(d4, u0, d3); Q0 = fmaf(Q0, u0, d2); Q0 = fmaf(Q0, u0, d1);
            float Q1 = fmaf(d4, u1, d3); Q1 = fmaf(Q1, u1, d2); Q1 = fmaf(Q1, u1, d1);
            val = (Q0 * u0 - Q1 * u1) / fmaf(1024.f, PC0, Ss);  // d0 cancels
        } else {
            const float EC  = LOG2E * Ct;
            const float Ls2 = LOG2E * s2a;
            #pragma unroll
            for (int j = 0; j < 16; ++j) {
                const float4 a = tab[j];
                const float q = fmaf(g0, a.y, fmaf(g1, a.z, fmaf(g2, a.w, a.x)));
                if (j & 1) {
                    t1O = __builtin_amdgcn_fmed3f(t0O, t1O, q); t0O = fmaxf(t0O, q);
                } else {
                    t1E = __builtin_amdgcn_fmed3f(t0E, t1E, q); t0E = fmaxf(t0E, q);
                }
                const float w = __builtin_amdgcn_exp2f(
                    fmaf(EC, __builtin_amdgcn_exp2f(q), -Ls2));
                if (j & 1) S1 += w; else S0 += w;
            }
            float t0 = fmaxf(t0E, t0O);
            float t1 = fmaxf(fminf(t0E, t0O), fmaxf(t1E, t1O));
            float S  = S0 + S1;
            red64(t0, t1, S);
            const float t0s = rlane_f(t0, 63);
            const float t1s = rlane_f(t1, 63);
            const float Ss  = rlane_f(S, 63);
            const float u0 = __builtin_amdgcn_exp2f(t0s);
            const float u1 = __builtin_amdgcn_exp2f(t1s);
            const float w0 = __builtin_amdgcn_exp2f(fmaf(EC, u0, -Ls2));
            val = w0 * (1.f - __builtin_amdgcn_exp2f(EC * (u1 - u0))) / Ss;
        }

        res = (lane == o) ? val : res;             // lane o keeps output o
    }

    if (lane < 16) out[b * 32768 + obase + lane] = res;  // coalesced store
}

extern "C" void kernel_launch(void* const* d_in, const int* in_sizes, int n_in,
                              void* d_out, int out_size, void* d_ws, size_t ws_size,
                              hipStream_t stream) {
    const float* xyz  = (const float*)d_in[0];
    const float* grid = (const float*)d_in[1];
    const float* s1   = (const float*)d_in[2];
    const float* s2   = (const float*)d_in[3];
    float* out        = (float*)d_out;
    hipLaunchKernelGGL(p2v_kernel, dim3(2048), dim3(256), 0, stream,
                       xyz, grid, s1, s2, out);
}

// Round 13
// 93.900 us; speedup vs baseline: 1.2052x; 1.2052x over previous
//
#include <hip/hip_runtime.h>
#include <math.h>

// P2V: out[b,dhw] = top2-margin over n of softmax_n( |s2| * exp(-|s1| * dist) )
// dist = |x|^2 + |g|^2 - 2 x.g
//
// Round 12 kernel, resubmitted (R12 bench was a container infra failure;
// never ran). Model fitting all rounds: dur = max(LDS-port, VALU).
//   R10: 8192 ds_read_b128/CU x 12cyc = 98K cyc = 41us LDS floor (>29us VALU)
// -> halve the LDS term by serving TWO outputs per table read (quad handles
// outputs dhwA, dhwA+64; one ds_read_b128 feeds both q_A and q_B).
// Per CU: 4096 ds_read = 20.5us LDS; VALU ~29us -> VALU-bound now.
// R11 lesson: compiler won't keep arrays VGPR-resident; this needs only ~10
// extra scalars. R9 lesson: packed f32 is not a lever (scalar fma saturates).
//
// Math (= R10): q = -c1|x|^2 + 2c1(x.g), c1=log2e*|s1|; u = 2^q; v = Ct*u,
//   Ct = |s2|*2^(-c1|g|^2); top-2 of v == top-2 of q (monotone).
//   fast (s2a<=1): e^v ~ PC0 + u*Q(u) (deg-4 minimax, Ct^k folded into Q);
//     S_true = 1024*PC0 + sum(Q(u)u);  num = exact exp2: e^{v0} - e^{v1}.
//   general: S = sum 2^(EC*2^q - Ls2); out = 2^(EC*u0-Ls2)(1-2^(EC(u1-u0)))/S.

#define LOG2E 1.44269504088896340736f
// deg-4 minimax (Chebyshev) coeffs for e^x on [0,1], abs err <= 2.8e-5
#define PC0 1.0000247f
#define PC1 0.9987113f
#define PC2 0.5099871f
#define PC3 0.1399751f
#define PC4 0.0695533f

__device__ __forceinline__ void qmerge(float& t0, float& t1, float& S) {
    #pragma unroll
    for (int m = 1; m <= 2; m <<= 1) {
        const float o0 = __shfl_xor(t0, m);
        const float o1 = __shfl_xor(t1, m);
        const float oS = __shfl_xor(S, m);
        t1 = fmaxf(fminf(t0, o0), fmaxf(t1, o1));
        t0 = fmaxf(t0, o0);
        S += oS;
    }
}

__global__ __launch_bounds__(256, 4) void p2v_kernel(
    const float* __restrict__ xyz,   // (B=4, C=3, N=1024)
    const float* __restrict__ grid,  // (C=3, 32768)
    const float* __restrict__ s1,
    const float* __restrict__ s2,
    float* __restrict__ out)         // (B=4, 32768)
{
    __shared__ float4 A[1024];       // 16 KB per-n table for this block's b

    const int tid  = threadIdx.x;
    const int b    = blockIdx.x >> 8;           // 256 blocks per b
    const int k    = blockIdx.x & 255;          // 128 outputs per block
    const int quad = tid >> 2;                  // 64 quads
    const int c    = tid & 3;                   // n-chunk within quad
    const int dhwA = (k << 7) + quad;           // quad's output #1
    const int dhwB = dhwA + 64;                 // quad's output #2

    const float s1a = fabsf(s1[0]);
    const float s2a = fabsf(s2[0]);
    const float c1  = LOG2E * s1a;

    const float* xb = xyz + b * 3072;
    #pragma unroll
    for (int i = 0; i < 4; ++i) {
        const int n = tid + i * 256;
        const float x = xb[n], y = xb[1024 + n], z = xb[2048 + n];
        const float x2 = fmaf(x, x, fmaf(y, y, z * z));
        A[n] = make_float4(-c1 * x2, 2.f * c1 * x, 2.f * c1 * y, 2.f * c1 * z);
    }
    __syncthreads();

    const float gA0 = grid[dhwA], gA1 = grid[32768 + dhwA], gA2 = grid[65536 + dhwA];
    const float gB0 = grid[dhwB], gB1 = grid[32768 + dhwB], gB2 = grid[65536 + dhwB];
    const float CtA = s2a * __builtin_amdgcn_exp2f(
        -c1 * fmaf(gA0, gA0, fmaf(gA1, gA1, gA2 * gA2)));
    const float CtB = s2a * __builtin_amdgcn_exp2f(
        -c1 * fmaf(gB0, gB0, fmaf(gB1, gB1, gB2 * gB2)));

    const float4* Ac = A + c;
    float t0A = -INFINITY, t1A = -INFINITY, t0B = -INFINITY, t1B = -INFINITY;
    float SA0 = 0.f, SA1 = 0.f, SB0 = 0.f, SB1 = 0.f;

    if (s2a <= 1.0f) {
        // ---- fast path: 1 trans per (output,n) pair ----
        const float CtA2 = CtA * CtA, CtB2 = CtB * CtB;
        const float d1A = PC1 * CtA, d1B = PC1 * CtB;
        const float d2A = PC2 * CtA2, d2B = PC2 * CtB2;
        const float d3A = PC3 * CtA2 * CtA, d3B = PC3 * CtB2 * CtB;
        const float d4A = PC4 * CtA2 * CtA2, d4B = PC4 * CtB2 * CtB2;

        #pragma unroll 8
        for (int i = 0; i < 256; ++i) {
            const float4 a = Ac[i << 2];        // ONE read feeds BOTH outputs
            const float qA = fmaf(gA0, a.y, fmaf(gA1, a.z, fmaf(gA2, a.w, a.x)));
            const float qB = fmaf(gB0, a.y, fmaf(gB1, a.z, fmaf(gB2, a.w, a.x)));
            t1A = __builtin_amdgcn_fmed3f(t0A, t1A, qA); t0A = fmaxf(t0A, qA);
            t1B = __builtin_amdgcn_fmed3f(t0B, t1B, qB); t0B = fmaxf(t0B, qB);
            const float uA = __builtin_amdgcn_exp2f(qA);
            const float uB = __builtin_amdgcn_exp2f(qB);
            float QA = fmaf(d4A, uA, d3A);
            float QB = fmaf(d4B, uB, d3B);
            QA = fmaf(QA, uA, d2A); QB = fmaf(QB, uB, d2B);
            QA = fmaf(QA, uA, d1A); QB = fmaf(QB, uB, d1B);
            if (i & 1) { SA1 = fmaf(QA, uA, SA1); SB1 = fmaf(QB, uB, SB1); }
            else       { SA0 = fmaf(QA, uA, SA0); SB0 = fmaf(QB, uB, SB0); }
        }
    } else {
        // ---- general fallback: shifted 2-exp path (any s2a) ----
        const float ECA = LOG2E * CtA, ECB = LOG2E * CtB;
        const float Ls2 = LOG2E * s2a;
        #pragma unroll 8
        for (int i = 0; i < 256; ++i) {
            const float4 a = Ac[i << 2];
            const float qA = fmaf(gA0, a.y, fmaf(gA1, a.z, fmaf(gA2, a.w, a.x)));
            const float qB = fmaf(gB0, a.y, fmaf(gB1, a.z, fmaf(gB2, a.w, a.x)));
            t1A = __builtin_amdgcn_fmed3f(t0A, t1A, qA); t0A = fmaxf(t0A, qA);
            t1B = __builtin_amdgcn_fmed3f(t0B, t1B, qB); t0B = fmaxf(t0B, qB);
            const float wA = __builtin_amdgcn_exp2f(
                fmaf(ECA, __builtin_amdgcn_exp2f(qA), -Ls2));
            const float wB = __builtin_amdgcn_exp2f(
                fmaf(ECB, __builtin_amdgcn_exp2f(qB), -Ls2));
            if (i & 1) { SA1 += wA; SB1 += wB; }
            else       { SA0 += wA; SB0 += wB; }
        }
    }

    float SA = SA0 + SA1, SB = SB0 + SB1;
    qmerge(t0A, t1A, SA);
    qmerge(t0B, t1B, SB);

    if (c == 0) {
        float* ob = out + b * 32768;
        const float u0A = __builtin_amdgcn_exp2f(t0A);
        const float u1A = __builtin_amdgcn_exp2f(t1A);
        const float u0B = __builtin_amdgcn_exp2f(t0B);
        const float u1B = __builtin_amdgcn_exp2f(t1B);
        const float ECA = LOG2E * CtA, ECB = LOG2E * CtB;
        if (s2a <= 1.0f) {
            // exact exp2 numerator; poly only in S (d0 hoisted)
            const float numA = __builtin_amdgcn_exp2f(ECA * u0A)
                             - __builtin_amdgcn_exp2f(ECA * u1A);
            const float numB = __builtin_amdgcn_exp2f(ECB * u0B)
                             - __builtin_amdgcn_exp2f(ECB * u1B);
            ob[dhwA] = numA / fmaf(1024.f, PC0, SA);
            ob[dhwB] = numB / fmaf(1024.f, PC0, SB);
        } else {
            const float Ls2 = LOG2E * s2a;
            const float w0A = __builtin_amdgcn_exp2f(fmaf(ECA, u0A, -Ls2));
            const float w0B = __builtin_amdgcn_exp2f(fmaf(ECB, u0B, -Ls2));
            ob[dhwA] = w0A * (1.f - __builtin_amdgcn_exp2f(ECA * (u1A - u0A))) / SA;
            ob[dhwB] = w0B * (1.f - __builtin_amdgcn_exp2f(ECB * (u1B - u0B))) / SB;
        }
    }
}

extern "C" void kernel_launch(void* const* d_in, const int* in_sizes, int n_in,
                              void* d_out, int out_size, void* d_ws, size_t ws_size,
                              hipStream_t stream) {
    const float* xyz  = (const float*)d_in[0];
    const float* grid = (const float*)d_in[1];
    const float* s1   = (const float*)d_in[2];
    const float* s2   = (const float*)d_in[3];
    float* out        = (float*)d_out;
    hipLaunchKernelGGL(p2v_kernel, dim3(1024), dim3(256), 0, stream,
                       xyz, grid, s1, s2, out);
}